// Round 9
// baseline (276.235 us; speedup 1.0000x reference)
//
#include <hip/hip_runtime.h>
#include <hip/hip_bf16.h>

// B=64, T=21, E=H=512, V=10000. fp32 in/out.
// gates = x@W_ih^T + h@W_hh^T + (b_ih+b_hh); i,f,g,o; out = h@W_lin^T + b_lin.
// SINGLE persistent kernel: conversions + xih GEMM + LSTM recurrence + out GEMM.
// h-exchange: chunk-major ghh/ghl; ONE per-block wave-arrival counter flgC
// (target 8) published per-wave after its own vmcnt(0) -> no publish barriers,
// no spinB leg. Split accumulators halve the dependent-MFMA chain; fast tanh.

#define NB 64
#define NT 21
#define NE 512
#define NH 512
#define NV 10000
#define G4 2048
#define FLGD 16   // dwords per flag slot (64B line padding)

typedef __attribute__((ext_vector_type(8))) short bf16x8;
typedef __attribute__((ext_vector_type(4))) float f32x4;
typedef __attribute__((ext_vector_type(4))) unsigned short u16x4;

// ---- workspace layout (bytes) ----
#define OFF_WIH_HI   0UL
#define OFF_WIH_LO   2097152UL
#define OFF_WLIN_HI  8388608UL     // 10112*512*2
#define OFF_XSEQ_HI  18743296UL    // 1408*512*2
#define OFF_XSEQ_LO  20185088UL
#define OFF_BIAS     21626880UL    // 2048*4
#define OFF_XIH      21635072UL    // 21*64*2048*4
#define OFF_GHH      32645120UL    // 2 x 64*512 bf16 h-hi, CHUNK-MAJOR [j][row][8]
#define OFF_GHL      32776192UL    // 2 x 64*512 bf16 h-lo, CHUNK-MAJOR [j][row][8]
#define OFF_C        32907264UL    // flgC[21][32] x 64B (wave-arrival counters)
#define OFF_SLB      32950272UL    // slab counters [0..20], convA @24, convB @25
// (single memset covers OFF_C .. OFF_SLB+1664 = 44672 B)
#define OFF_HBUF     33038336UL    // 20*64*512 bf16 (sc-visible mid-kernel)
// end 34,351,616 B

__device__ inline unsigned short f2bf(float f) {
    unsigned int u = __float_as_uint(f);
    unsigned int r = u + 0x7FFFu + ((u >> 16) & 1u);
    return (unsigned short)(r >> 16);
}
__device__ inline float bf2f(unsigned short s) {
    return __uint_as_float(((unsigned int)s) << 16);
}
__device__ inline float tanhf_fast(float x) {
    // tanh(x) = (e^{2x}-1)/(e^{2x}+1); clamp avoids inf/inf
    float xc = fminf(20.f, fmaxf(-20.f, x));
    float e = __expf(2.f * xc);
    return (e - 1.f) / (e + 1.f);
}

__device__ __forceinline__ void gl_lds16(const unsigned short* g, unsigned short* l) {
    auto gp = (const __attribute__((address_space(1))) unsigned int*)(unsigned long long)(const void*)g;
    auto lp = (__attribute__((address_space(3))) unsigned int*)(unsigned int)(unsigned long long)(void*)l;
    __builtin_amdgcn_global_load_lds(gp, lp, 16, 0, 0);
}

// DMA that reads at the coherence point (bypass L1+L2): aux = sc0|sc1 = 1|16.
__device__ __forceinline__ void gl_lds16_sc(const unsigned short* g, unsigned short* l) {
    auto gp = (const __attribute__((address_space(1))) unsigned int*)(unsigned long long)(const void*)g;
    auto lp = (__attribute__((address_space(3))) unsigned int*)(unsigned int)(unsigned long long)(void*)l;
    __builtin_amdgcn_global_load_lds(gp, lp, 16, 0, 17);
}

// Write-through stores visible at the coherence point.
__device__ __forceinline__ void st4_sc(unsigned int* p, unsigned int v) {
    asm volatile("global_store_dword %0, %1, off sc0 sc1" :: "v"(p), "v"(v) : "memory");
}
__device__ __forceinline__ void st8_sc(unsigned short* p, u16x4 v) {
    asm volatile("global_store_dwordx2 %0, %1, off sc0 sc1" :: "v"(p), "v"(v) : "memory");
}
__device__ __forceinline__ void st16_sc(float* p, f32x4 v) {
    asm volatile("global_store_dwordx4 %0, %1, off sc0 sc1" :: "v"(p), "v"(v) : "memory");
}

// ---------------- fused persistent (the whole pipeline) ----------------
__global__ __launch_bounds__(512) void fused_all(
    const float* __restrict__ features, const float* __restrict__ cap,
    const float* __restrict__ W_ih_f, const float* __restrict__ W_hh_f,
    const float* __restrict__ b_ih, const float* __restrict__ b_hh,
    const float* __restrict__ W_lin_f, const float* __restrict__ b_lin,
    float* __restrict__ out, unsigned char* __restrict__ ws)
{
    __shared__ unsigned short Hhi[64 * 512];   // lstm: h-hi image | workers: GEMM tiles
    __shared__ unsigned short Hlo[64 * 512];   // lstm: h-lo image
    __shared__ float glf[4096];                // lstm: gate values
    const int tid = threadIdx.x;
    const int lane = tid & 63, wv = tid >> 6;
    const int mf = lane & 15, kg = lane >> 4;

    unsigned int* __restrict__ flgC = (unsigned int*)(ws + OFF_C);
    unsigned int* __restrict__ slb  = (unsigned int*)(ws + OFF_SLB);
    unsigned short* __restrict__ hbuf = (unsigned short*)(ws + OFF_HBUF);
    const float* __restrict__ bias = (const float*)(ws + OFF_BIAS);
    float* __restrict__ xih_base = (float*)(ws + OFF_XIH);

    if (blockIdx.x < 32) {
        // ================= LSTM recurrence =================
        const int bc = blockIdx.x;
        const int q = wv & 3;        // gate quadrant
        const int mh = wv >> 2;      // row half

        unsigned short* __restrict__ ghh = (unsigned short*)(ws + OFF_GHH);
        unsigned short* __restrict__ ghl = (unsigned short*)(ws + OFF_GHL);

        // ---- convert OWN W_hh slice (fp32 -> hi/lo bf16 fragments) ----
        bf16x8 bh[16], blo[16];
#pragma unroll
        for (int j = 0; j < 16; ++j) {
            const float* src = W_hh_f + (size_t)(q * 512 + bc * 16 + mf) * 512 + j * 32 + kg * 8;
            float4 w0 = *(const float4*)src;
            float4 w1 = *(const float4*)(src + 4);
            float ff[8] = {w0.x, w0.y, w0.z, w0.w, w1.x, w1.y, w1.z, w1.w};
#pragma unroll
            for (int e = 0; e < 8; ++e) {
                const unsigned short h = f2bf(ff[e]);
                bh[j][e] = (short)h;
                blo[j][e] = (short)f2bf(ff[e] - bf2f(h));
            }
        }

        // ---- per-thread cell mapping: 2 ADJACENT cols of one row ----
        const int crow = tid >> 3;           // batch row 0..63
        const int cp = tid & 7;              // col-pair 0..7
        const int c0 = bc * 16 + cp * 2;     // first hidden col
        const int jch = bc * 2 + (cp >> 2);  // chunk index (chunk-major layout)
        const int sw = (jch * 64 + crow) * 8 + ((cp * 2) & 7);  // elem offset
        float creg0 = 0.f, creg1 = 0.f;

        float2 xp[4];
        auto load_xp = [&](int tt) {
            const float* __restrict__ xq = xih_base + (size_t)tt * NB * G4;
#pragma unroll
            for (int g2 = 0; g2 < 4; ++g2)
                xp[g2] = *(const float2*)&xq[crow * G4 + g2 * 512 + c0];
        };

        // wait for xih slab 0 (workers produce it), then prefetch
        if (tid == 0) {
            while (__hip_atomic_load(&slb[0], __ATOMIC_RELAXED, __HIP_MEMORY_SCOPE_AGENT) < 16u)
                __builtin_amdgcn_s_sleep(1);
        }
        __syncthreads();
        load_xp(0);

        for (int t = 0; t < NT; ++t) {
            f32x4 accA[2], accB[2], accC[2];
#pragma unroll
            for (int m = 0; m < 2; ++m) {
                accA[m] = (f32x4){0.f, 0.f, 0.f, 0.f};
                accB[m] = (f32x4){0.f, 0.f, 0.f, 0.f};
                accC[m] = (f32x4){0.f, 0.f, 0.f, 0.f};
            }

            if (t > 0) {
                const int rd = (t + 1) & 1;
                const unsigned short* __restrict__ ghh_r = ghh + rd * (NB * NH);
                const unsigned short* __restrict__ ghl_r = ghl + rd * (NB * NH);

                // ---- ONE combined spin: lanes 0-3 watch my 4 producers' wave
                //      counters (==8 -> ALL their stores drained); lane 4
                //      watches the xih slab counter; ballot exit ----
                {
                    const unsigned int* p = flgC + ((size_t)(t - 1) * 32 + bc) * FLGD;
                    unsigned int tgt = 0u;
                    if (lane < 4)       { p = flgC + ((size_t)(t - 1) * 32 + wv * 4 + lane) * FLGD; tgt = 8u; }
                    else if (lane == 4) { p = slb + (size_t)t * FLGD; tgt = 16u; }
                    while (__any(__hip_atomic_load(p, __ATOMIC_RELAXED, __HIP_MEMORY_SCOPE_AGENT) < tgt))
                        __builtin_amdgcn_s_sleep(1);
                }
                __builtin_amdgcn_sched_barrier(0);
                // ---- hi + lo DMA back-to-back (16 insts; full drain proven by ==8) ----
#pragma unroll
                for (int pp = 0; pp < 4; ++pp) {
                    const int jj = (wv * 4 + pp) * 2;   // chunk pair base
                    gl_lds16_sc(ghh_r + (jj    ) * 512 + lane * 8, &Hhi[(jj    ) * 512 + lane * 8]);
                    gl_lds16_sc(ghh_r + (jj + 1) * 512 + lane * 8, &Hhi[(jj + 1) * 512 + lane * 8]);
                }
#pragma unroll
                for (int pp = 0; pp < 4; ++pp) {
                    const int jj = (wv * 4 + pp) * 2;
                    gl_lds16_sc(ghl_r + (jj    ) * 512 + lane * 8, &Hlo[(jj    ) * 512 + lane * 8]);
                    gl_lds16_sc(ghl_r + (jj + 1) * 512 + lane * 8, &Hlo[(jj + 1) * 512 + lane * 8]);
                }
                // hi half retired (8 oldest of 16); barrier -> all waves' hi done
                asm volatile("s_waitcnt vmcnt(8)" ::: "memory");
                __builtin_amdgcn_s_barrier();
                load_xp(t);   // latency hides under hi MFMA
                // ---- hi passes: two INDEPENDENT accumulator chains ----
#pragma unroll
                for (int kt = 0; kt < 16; ++kt) {
                    const int j = kt * 4 + kg;
#pragma unroll
                    for (int m = 0; m < 2; ++m) {
                        const int row = mh * 32 + m * 16 + mf;
                        bf16x8 a_hi = *(const bf16x8*)&Hhi[(j * 64 + row) * 8];
                        accA[m] = __builtin_amdgcn_mfma_f32_16x16x32_bf16(a_hi, bh[kt], accA[m], 0, 0, 0);
                        accB[m] = __builtin_amdgcn_mfma_f32_16x16x32_bf16(a_hi, blo[kt], accB[m], 0, 0, 0);
                    }
                }
                asm volatile("s_waitcnt vmcnt(0)" ::: "memory");
                __builtin_amdgcn_s_barrier();
                // ---- lo pass: third independent chain ----
#pragma unroll
                for (int kt = 0; kt < 16; ++kt) {
                    const int j = kt * 4 + kg;
#pragma unroll
                    for (int m = 0; m < 2; ++m) {
                        const int row = mh * 32 + m * 16 + mf;
                        bf16x8 a_lo = *(const bf16x8*)&Hlo[(j * 64 + row) * 8];
                        accC[m] = __builtin_amdgcn_mfma_f32_16x16x32_bf16(a_lo, bh[kt], accC[m], 0, 0, 0);
                    }
                }
            }

            // ---- sum chains, gate values straight to LDS ----
#pragma unroll
            for (int m = 0; m < 2; ++m) {
                f32x4 acc = (accA[m] + accB[m]) + accC[m];
                const int row = mh * 32 + m * 16 + kg * 4;
#pragma unroll
                for (int r = 0; r < 4; ++r)
                    glf[(q * 64 + row + r) * 16 + mf] = acc[r];
            }
            __syncthreads();

            // ---- LSTM cell: 2 adjacent cols/thread, packed sc-stores ----
            {
                unsigned short* __restrict__ ghh_w = ghh + (t & 1) * (NB * NH);
                unsigned short* __restrict__ ghl_w = ghl + (t & 1) * (NB * NH);
                const float2 g0 = *(const float2*)&glf[(0 * 64 + crow) * 16 + cp * 2];
                const float2 g1 = *(const float2*)&glf[(1 * 64 + crow) * 16 + cp * 2];
                const float2 g2 = *(const float2*)&glf[(2 * 64 + crow) * 16 + cp * 2];
                const float2 g3 = *(const float2*)&glf[(3 * 64 + crow) * 16 + cp * 2];
                const float gi0 = g0.x + xp[0].x, gi1 = g0.y + xp[0].y;
                const float gf0 = g1.x + xp[1].x, gf1 = g1.y + xp[1].y;
                const float gg0 = g2.x + xp[2].x, gg1 = g2.y + xp[2].y;
                const float go0 = g3.x + xp[3].x, go1 = g3.y + xp[3].y;
                const float i0 = 1.f / (1.f + __expf(-gi0)), i1 = 1.f / (1.f + __expf(-gi1));
                const float f0 = 1.f / (1.f + __expf(-gf0)), f1 = 1.f / (1.f + __expf(-gf1));
                const float ga0 = tanhf_fast(gg0),           ga1 = tanhf_fast(gg1);
                const float o0 = 1.f / (1.f + __expf(-go0)), o1 = 1.f / (1.f + __expf(-go1));
                const float cn0 = f0 * creg0 + i0 * ga0;
                const float cn1 = f1 * creg1 + i1 * ga1;
                creg0 = cn0; creg1 = cn1;
                const float h0 = o0 * tanhf_fast(cn0);
                const float h1 = o1 * tanhf_fast(cn1);
                const unsigned short hi0 = f2bf(h0), hi1 = f2bf(h1);
                const unsigned short lo0 = f2bf(h0 - bf2f(hi0)), lo1 = f2bf(h1 - bf2f(hi1));
                const unsigned int hpack = (unsigned int)hi0 | ((unsigned int)hi1 << 16);
                const unsigned int lpack = (unsigned int)lo0 | ((unsigned int)lo1 << 16);
                st4_sc((unsigned int*)&ghh_w[sw], hpack);
                st4_sc((unsigned int*)&ghl_w[sw], lpack);
                const int sl = (t == 0) ? 0 : t - 1;   // t=0 dummy, overwritten at t=1
                st4_sc((unsigned int*)&hbuf[(size_t)sl * (NB * NH) + crow * NH + c0], hpack);
            }

            // ---- per-wave publish: own stores drained -> arrive (NO barriers) ----
            asm volatile("s_waitcnt vmcnt(0)" ::: "memory");   // this wave's 3 stores
            if (lane == 0)
                __hip_atomic_fetch_add(flgC + ((size_t)t * 32 + bc) * FLGD, 1u,
                                       __ATOMIC_RELAXED, __HIP_MEMORY_SCOPE_AGENT);
        }
        asm volatile("s_waitcnt vmcnt(0)" ::: "memory");
        return;
    }

    // ================= workers =================
    const int g = blockIdx.x - 32;          // 0..223
    const int mw2 = (wv >> 2) * 32, nw2 = (wv & 3) * 32;

    // ---- stage A: input conversions (workers only, 224 blocks) ----
    {
        unsigned short* wih_hi = (unsigned short*)(ws + OFF_WIH_HI);
        unsigned short* wih_lo = (unsigned short*)(ws + OFF_WIH_LO);
        unsigned short* xs_hi = (unsigned short*)(ws + OFF_XSEQ_HI);
        unsigned short* xs_lo = (unsigned short*)(ws + OFF_XSEQ_LO);
        float* bias_w = (float*)(ws + OFF_BIAS);
        int idx = g * 512 + tid;
        for (int it = 0; it < 4; ++it, idx += 114688) {
            if (idx < 262144) {
                const int i4 = idx * 4;
                float4 w = *(const float4*)(W_ih_f + i4);
                u16x4 hi, lo;
                hi.x = f2bf(w.x); lo.x = f2bf(w.x - bf2f(hi.x));
                hi.y = f2bf(w.y); lo.y = f2bf(w.y - bf2f(hi.y));
                hi.z = f2bf(w.z); lo.z = f2bf(w.z - bf2f(hi.z));
                hi.w = f2bf(w.w); lo.w = f2bf(w.w - bf2f(hi.w));
                st8_sc(wih_hi + i4, hi);
                st8_sc(wih_lo + i4, lo);
            } else if (idx < 434176) {
                const int i4 = (idx - 262144) * 4;
                const int e = i4 & 511;
                const int b = (i4 >> 9) & 63;
                const int t2 = i4 >> 15;
                float4 x = (t2 == 0) ? *(const float4*)(features + b * NE + e)
                                     : *(const float4*)(cap + b * (NT * NE) + (t2 - 1) * NE + e);
                u16x4 hi, lo;
                hi.x = f2bf(x.x); lo.x = f2bf(x.x - bf2f(hi.x));
                hi.y = f2bf(x.y); lo.y = f2bf(x.y - bf2f(hi.y));
                hi.z = f2bf(x.z); lo.z = f2bf(x.z - bf2f(hi.z));
                hi.w = f2bf(x.w); lo.w = f2bf(x.w - bf2f(hi.w));
                st8_sc(xs_hi + i4, hi);
                st8_sc(xs_lo + i4, lo);
            } else if (idx < 434688) {
                const int j = (idx - 434176) * 4;
                float4 a = *(const float4*)(b_ih + j);
                float4 b = *(const float4*)(b_hh + j);
                f32x4 s;
                s[0] = a.x + b.x; s[1] = a.y + b.y; s[2] = a.z + b.z; s[3] = a.w + b.w;
                st16_sc(bias_w + j, s);
            }
        }
        asm volatile("s_waitcnt vmcnt(0)" ::: "memory");
        __syncthreads();
        if (tid == 0) {
            __hip_atomic_fetch_add(&slb[24 * FLGD], 1u, __ATOMIC_RELAXED, __HIP_MEMORY_SCOPE_AGENT);
            while (__hip_atomic_load(&slb[24 * FLGD], __ATOMIC_RELAXED, __HIP_MEMORY_SCOPE_AGENT) < 224u)
                __builtin_amdgcn_s_sleep(1);
        }
        __syncthreads();
    }

    // ---- stage 1: xih tiles (old gemm_a), earliest slabs first ----
    {
        const unsigned short* __restrict__ xh = (const unsigned short*)(ws + OFF_XSEQ_HI);
        const unsigned short* __restrict__ xl = (const unsigned short*)(ws + OFF_XSEQ_LO);
        const unsigned short* __restrict__ wih_h = (const unsigned short*)(ws + OFF_WIH_HI);
        const unsigned short* __restrict__ wih_l = (const unsigned short*)(ws + OFF_WIH_LO);

        unsigned short* Ah2 = Hhi;            // [2][2048] shorts
        unsigned short* Al2 = Hhi + 4096;
        unsigned short* Bh2 = Hhi + 8192;     // [2][4096] shorts
        unsigned short* Bl2 = Hhi + 16384;

        const int ntile = (g < 112) ? 2 : 1;
        for (int p = 0; p < ntile; ++p) {
            const int T = (p == 0) ? g : 224 + g;
            const int slab = T >> 4, ct = T & 15;
            const unsigned short* __restrict__ xhA = xh + (size_t)slab * 64 * 512;
            const unsigned short* __restrict__ xlA = xl + (size_t)slab * 64 * 512;

            auto stageA = [&](int buf, int k0) {
                if (tid < 256) {
                    const int s = tid, r = s >> 2, kc = (s & 3) * 8;
                    gl_lds16(xhA + (size_t)r * 512 + k0 + kc, &Ah2[buf * 2048 + s * 8]);
                    gl_lds16(xlA + (size_t)r * 512 + k0 + kc, &Al2[buf * 2048 + s * 8]);
                } else {
#pragma unroll
                    for (int h2 = 0; h2 < 2; ++h2) {
                        const int s = h2 * 256 + (tid - 256), r = s >> 2, kc = (s & 3) * 8;
                        gl_lds16(wih_h + (size_t)(ct * 128 + r) * 512 + k0 + kc, &Bh2[buf * 4096 + s * 8]);
                        gl_lds16(wih_l + (size_t)(ct * 128 + r) * 512 + k0 + kc, &Bl2[buf * 4096 + s * 8]);
                    }
                }
            };

            f32x4 acc2[2][2];
#pragma unroll
            for (int i = 0; i < 2; i++)
#pragma unroll
                for (int j = 0; j < 2; j++) acc2[i][j] = (f32x4){0.f, 0.f, 0.f, 0.f};

            stageA(0, 0);
            for (int kt = 0; kt < 16; ++kt) {
                __syncthreads();
                const int cur = kt & 1;
                if (kt < 15) stageA(cur ^ 1, (kt + 1) * 32);
                bf16x8 ah_[2], al_[2], bh_[2], bl_[2];
#pragma unroll
                for (int i = 0; i < 2; i++) {
                    ah_[i] = *(const bf16x8*)&Ah2[cur * 2048 + (mw2 + i * 16 + mf) * 32 + kg * 8];
                    al_[i] = *(const bf16x8*)&Al2[cur * 2048 + (mw2 + i * 16 + mf) * 32 + kg * 8];
                    bh_[i] = *(const bf16x8*)&Bh2[cur * 4096 + (nw2 + i * 16 + mf) * 32 + kg * 8];
                    bl_[i] = *(const bf16x8*)&Bl2[cur * 4096 + (nw2 + i * 16 + mf) * 32 + kg * 8];
                }
#pragma unroll
                for (int i = 0; i < 2; i++)
#pragma unroll
                    for (int j = 0; j < 2; j++) {
                        acc2[i][j] = __builtin_amdgcn_mfma_f32_16x16x32_bf16(ah_[i], bh_[j], acc2[i][j], 0, 0, 0);
                        acc2[i][j] = __builtin_amdgcn_mfma_f32_16x16x32_bf16(ah_[i], bl_[j], acc2[i][j], 0, 0, 0);
                        acc2[i][j] = __builtin_amdgcn_mfma_f32_16x16x32_bf16(al_[i], bh_[j], acc2[i][j], 0, 0, 0);
                    }
            }
            // epilogue: xih = acc + bias, sc-stores (visible mid-kernel)
#pragma unroll
            for (int i = 0; i < 2; i++)
#pragma unroll
                for (int j = 0; j < 2; j++) {
                    const int col = ct * 128 + nw2 + j * 16 + mf;
                    const float bb = bias[col];
#pragma unroll
                    for (int r = 0; r < 4; r++) {
                        const int row = slab * 64 + mw2 + i * 16 + kg * 4 + r;
                        st4_sc((unsigned int*)&xih_base[(size_t)row * G4 + col],
                               __float_as_uint(acc2[i][j][r] + bb));
                    }
                }
            asm volatile("s_waitcnt vmcnt(0)" ::: "memory");
            __syncthreads();   // all threads' xih stores at the coherence point
            if (tid == 0)
                __hip_atomic_fetch_add(&slb[slab * FLGD], 1u, __ATOMIC_RELAXED, __HIP_MEMORY_SCOPE_AGENT);
            __syncthreads();
        }
    }

    // ---- stage B: W_lin conversion (workers only; hidden under recurrence) ----
    {
        unsigned short* wlin_w = (unsigned short*)(ws + OFF_WLIN_HI);
        int idx = g * 512 + tid;
        for (int it = 0; it < 12; ++it, idx += 114688) {
            if (idx < 1280000) {
                const int i4 = idx * 4;
                float4 w = *(const float4*)(W_lin_f + i4);
                u16x4 hi;
                hi.x = f2bf(w.x); hi.y = f2bf(w.y); hi.z = f2bf(w.z); hi.w = f2bf(w.w);
                st8_sc(wlin_w + i4, hi);
            }
        }
        asm volatile("s_waitcnt vmcnt(0)" ::: "memory");
        __syncthreads();
        if (tid == 0) {
            __hip_atomic_fetch_add(&slb[25 * FLGD], 1u, __ATOMIC_RELAXED, __HIP_MEMORY_SCOPE_AGENT);
            while (__hip_atomic_load(&slb[25 * FLGD], __ATOMIC_RELAXED, __HIP_MEMORY_SCOPE_AGENT) < 224u)
                __builtin_amdgcn_s_sleep(1);
        }
        __syncthreads();
    }

    // ---- stage 2: streamed phase-C ----
    const unsigned short* __restrict__ wlin = (const unsigned short*)(ws + OFF_WLIN_HI);
    const int jt = g % 79;                  // fixed col tile -> B stays L2-resident
    const int rshare = g / 79;              // 0..2
    const int nshare = (jt < 66) ? 3 : 2;   // blocks sharing this col tile
    const int n0g = jt * 128;

    unsigned short* __restrict__ AsB = Hhi;          // [2][64*32]
    unsigned short* __restrict__ BsB = Hhi + 4096;   // [2][128*32]

    for (int tt = rshare; tt < NT - 1; tt += nshare) {
        // wait until h(tt+1) fully drained (all 8 waves arrived)
        if (wv == 0) {
            const unsigned int* fp = flgC + ((size_t)(tt + 1) * 32 + (lane & 31)) * FLGD;
            while (__hip_atomic_load(fp, __ATOMIC_RELAXED, __HIP_MEMORY_SCOPE_AGENT) < 8u)
                __builtin_amdgcn_s_sleep(2);
        }
        __syncthreads();

        const unsigned short* __restrict__ hbA = hbuf + (size_t)tt * (NB * NH);
        auto stageC = [&](int buf, int k0) {
            if (tid < 256) {                 // waves 0..3: A (64x32), sc-reads
                const int s = tid;
                const int r = s >> 2, kcol = (s & 3) * 8;
                gl_lds16_sc(hbA + (size_t)r * 512 + k0 + kcol, &AsB[buf * 2048 + s * 8]);
            } else {                         // waves 4..7: B (128x32)
#pragma unroll
                for (int h2 = 0; h2 < 2; ++h2) {
                    const int s = h2 * 256 + (tid - 256);
                    const int r = s >> 2, kcol = (s & 3) * 8;
                    gl_lds16(wlin + (size_t)(n0g + r) * 512 + k0 + kcol, &BsB[buf * 4096 + s * 8]);
                }
            }
        };

        f32x4 acc2[2][2];
#pragma unroll
        for (int i = 0; i < 2; i++)
#pragma unroll
            for (int j = 0; j < 2; j++) acc2[i][j] = (f32x4){0.f, 0.f, 0.f, 0.f};

        stageC(0, 0);
        for (int kt = 0; kt < 16; ++kt) {
            __syncthreads();
            const int cur = kt & 1;
            if (kt < 15) stageC(cur ^ 1, (kt + 1) * 32);
            bf16x8 af[2], bfv[2];
#pragma unroll
            for (int i = 0; i < 2; i++) {
                af[i]  = *(const bf16x8*)&AsB[cur * 2048 + (mw2 + i * 16 + mf) * 32 + kg * 8];
                bfv[i] = *(const bf16x8*)&BsB[cur * 4096 + (nw2 + i * 16 + mf) * 32 + kg * 8];
            }
#pragma unroll
            for (int i = 0; i < 2; i++)
#pragma unroll
                for (int j = 0; j < 2; j++)
                    acc2[i][j] = __builtin_amdgcn_mfma_f32_16x16x32_bf16(af[i], bfv[j], acc2[i][j], 0, 0, 0);
        }
#pragma unroll
        for (int i = 0; i < 2; i++)
#pragma unroll
            for (int j = 0; j < 2; j++) {
                const int col = n0g + nw2 + j * 16 + mf;
                if (col < NV) {
                    const float bl = b_lin[col];
#pragma unroll
                    for (int r = 0; r < 4; r++) {
                        const int b_ = mw2 + i * 16 + kg * 4 + r;   // batch row
                        out[(size_t)b_ * ((NT - 1) * NV) + (size_t)tt * NV + col] = acc2[i][j][r] + bl;
                    }
                }
            }
        __syncthreads();   // tile reads done before next job restages
    }
}

extern "C" void kernel_launch(void* const* d_in, const int* in_sizes, int n_in,
                              void* d_out, int out_size, void* d_ws, size_t ws_size,
                              hipStream_t stream)
{
    const float* features = (const float*)d_in[0];
    const float* cap      = (const float*)d_in[1];
    const float* W_ih     = (const float*)d_in[2];
    const float* W_hh     = (const float*)d_in[3];
    const float* b_ih     = (const float*)d_in[4];
    const float* b_hh     = (const float*)d_in[5];
    const float* W_lin    = (const float*)d_in[6];
    const float* b_lin    = (const float*)d_in[7];
    float* out = (float*)d_out;
    unsigned char* ws = (unsigned char*)d_ws;

    // single contiguous memset: flgC + slab counters
    (void)hipMemsetAsync(ws + OFF_C, 0, 44672, stream);

    hipLaunchKernelGGL(fused_all, dim3(256), dim3(512), 0, stream,
                       features, cap, W_ih, W_hh, b_ih, b_hh, W_lin, b_lin, out, ws);
}

// Round 10
// 246.099 us; speedup vs baseline: 1.1225x; 1.1225x over previous
//
#include <hip/hip_runtime.h>
#include <hip/hip_bf16.h>

// B=64, T=21, E=H=512, V=10000. fp32 in/out.
// gates = x@W_ih^T + h@W_hh^T + (b_ih+b_hh); i,f,g,o; out = h@W_lin^T + b_lin.
// prep kernel (full-GPU conversions of W_ih/xseq/bias) + fused persistent
// kernel (LSTM recurrence + streamed xih GEMM + W_lin conversion + out GEMM).
// h-exchange: chunk-major ghh/ghl; split flags (flagA = ghh drained via
// vmcnt(2), flagB = full drain) with single tid0 stores + raw barriers
// (round-8 proven scheme). Split accumulators + fast tanh in the cell.

#define NB 64
#define NT 21
#define NE 512
#define NH 512
#define NV 10000
#define G4 2048
#define FLGD 16   // dwords per flag slot (64B line padding)

typedef __attribute__((ext_vector_type(8))) short bf16x8;
typedef __attribute__((ext_vector_type(4))) float f32x4;
typedef __attribute__((ext_vector_type(4))) unsigned short u16x4;

// ---- workspace layout (bytes) ----
#define OFF_WIH_HI   0UL
#define OFF_WIH_LO   2097152UL
#define OFF_WLIN_HI  8388608UL     // 10112*512*2
#define OFF_XSEQ_HI  18743296UL    // 1408*512*2
#define OFF_XSEQ_LO  20185088UL
#define OFF_BIAS     21626880UL    // 2048*4
#define OFF_XIH      21635072UL    // 21*64*2048*4
#define OFF_GHH      32645120UL    // 2 x 64*512 bf16 h-hi, CHUNK-MAJOR [j][row][8]
#define OFF_GHL      32776192UL    // 2 x 64*512 bf16 h-lo, CHUNK-MAJOR [j][row][8]
#define OFF_C        32907264UL    // flagA[21][32] x 64B
#define OFF_CB       32950272UL    // flagB[21][32] x 64B
#define OFF_SLB      32993280UL    // slab counters [0..20], convB @25
// (single memset covers OFF_C .. OFF_SLB+1664 = 87680 B)
#define OFF_HBUF     33038336UL    // 20*64*512 bf16 (sc-visible mid-kernel)
// end 34,351,616 B

__device__ inline unsigned short f2bf(float f) {
    unsigned int u = __float_as_uint(f);
    unsigned int r = u + 0x7FFFu + ((u >> 16) & 1u);
    return (unsigned short)(r >> 16);
}
__device__ inline float bf2f(unsigned short s) {
    return __uint_as_float(((unsigned int)s) << 16);
}
__device__ inline float tanhf_fast(float x) {
    // tanh(x) = (e^{2x}-1)/(e^{2x}+1); clamp avoids inf/inf
    float xc = fminf(20.f, fmaxf(-20.f, x));
    float e = __expf(2.f * xc);
    return (e - 1.f) / (e + 1.f);
}

__device__ __forceinline__ void gl_lds16(const unsigned short* g, unsigned short* l) {
    auto gp = (const __attribute__((address_space(1))) unsigned int*)(unsigned long long)(const void*)g;
    auto lp = (__attribute__((address_space(3))) unsigned int*)(unsigned int)(unsigned long long)(void*)l;
    __builtin_amdgcn_global_load_lds(gp, lp, 16, 0, 0);
}

// DMA that reads at the coherence point (bypass L1+L2): aux = sc0|sc1 = 1|16.
__device__ __forceinline__ void gl_lds16_sc(const unsigned short* g, unsigned short* l) {
    auto gp = (const __attribute__((address_space(1))) unsigned int*)(unsigned long long)(const void*)g;
    auto lp = (__attribute__((address_space(3))) unsigned int*)(unsigned int)(unsigned long long)(void*)l;
    __builtin_amdgcn_global_load_lds(gp, lp, 16, 0, 17);
}

// Write-through stores visible at the coherence point.
__device__ __forceinline__ void st4_sc(unsigned int* p, unsigned int v) {
    asm volatile("global_store_dword %0, %1, off sc0 sc1" :: "v"(p), "v"(v) : "memory");
}
__device__ __forceinline__ void st8_sc(unsigned short* p, u16x4 v) {
    asm volatile("global_store_dwordx2 %0, %1, off sc0 sc1" :: "v"(p), "v"(v) : "memory");
}

// ---------------- prep: W_ih hi/lo + xseq hi/lo + bias (full-GPU) ----------------
__global__ __launch_bounds__(256) void prep_kernel(
    const float* __restrict__ features, const float* __restrict__ cap,
    const float* __restrict__ W_ih, const float* __restrict__ b_ih,
    const float* __restrict__ b_hh, unsigned char* __restrict__ ws)
{
    const int idx = blockIdx.x * 256 + threadIdx.x;
    unsigned short* wih_hi = (unsigned short*)(ws + OFF_WIH_HI);
    unsigned short* wih_lo = (unsigned short*)(ws + OFF_WIH_LO);
    unsigned short* xs_hi = (unsigned short*)(ws + OFF_XSEQ_HI);
    unsigned short* xs_lo = (unsigned short*)(ws + OFF_XSEQ_LO);
    float* bias = (float*)(ws + OFF_BIAS);

    if (idx < 262144) {
        const int i4 = idx * 4;
        float4 w = *(const float4*)(W_ih + i4);
        u16x4 hi, lo;
        hi.x = f2bf(w.x); lo.x = f2bf(w.x - bf2f(hi.x));
        hi.y = f2bf(w.y); lo.y = f2bf(w.y - bf2f(hi.y));
        hi.z = f2bf(w.z); lo.z = f2bf(w.z - bf2f(hi.z));
        hi.w = f2bf(w.w); lo.w = f2bf(w.w - bf2f(hi.w));
        *(u16x4*)(wih_hi + i4) = hi;
        *(u16x4*)(wih_lo + i4) = lo;
    } else if (idx < 434176) {
        const int i4 = (idx - 262144) * 4;
        const int e = i4 & 511;
        const int b = (i4 >> 9) & 63;
        const int t = i4 >> 15;
        float4 x = (t == 0) ? *(const float4*)(features + b * NE + e)
                            : *(const float4*)(cap + b * (NT * NE) + (t - 1) * NE + e);
        u16x4 hi, lo;
        hi.x = f2bf(x.x); lo.x = f2bf(x.x - bf2f(hi.x));
        hi.y = f2bf(x.y); lo.y = f2bf(x.y - bf2f(hi.y));
        hi.z = f2bf(x.z); lo.z = f2bf(x.z - bf2f(hi.z));
        hi.w = f2bf(x.w); lo.w = f2bf(x.w - bf2f(hi.w));
        *(u16x4*)(xs_hi + i4) = hi;
        *(u16x4*)(xs_lo + i4) = lo;
    } else if (idx < 434688) {
        const int j = (idx - 434176) * 4;
        float4 a = *(const float4*)(b_ih + j);
        float4 b = *(const float4*)(b_hh + j);
        *(float4*)(bias + j) = make_float4(a.x + b.x, a.y + b.y, a.z + b.z, a.w + b.w);
    }
}

// ---------------- fused persistent ----------------
// Grid = 256 blocks x 512 thr, 147456 B LDS -> 1 block/CU -> all co-resident.
// Blocks 0..31 : convert own W_hh slice to registers, wait xih slab 0, then
//   the 21-step recurrence (round-8 flag scheme; split accumulators, fast tanh).
// Blocks 32..255: xih tiles (early slabs first) -> W_lin conversion (stage B,
//   worker barrier) -> streamed phase-C out-slabs gated on flagB.
__global__ __launch_bounds__(512) void fused_all(
    const float* __restrict__ W_hh_f, const float* __restrict__ W_lin_f,
    const float* __restrict__ b_lin, float* __restrict__ out,
    unsigned char* __restrict__ ws)
{
    __shared__ unsigned short Hhi[64 * 512];   // lstm: h-hi image | workers: GEMM tiles
    __shared__ unsigned short Hlo[64 * 512];   // lstm: h-lo image
    __shared__ float glf[4096];                // lstm: gate values
    const int tid = threadIdx.x;
    const int lane = tid & 63, wv = tid >> 6;
    const int mf = lane & 15, kg = lane >> 4;

    unsigned int* __restrict__ flgA = (unsigned int*)(ws + OFF_C);
    unsigned int* __restrict__ flgB = (unsigned int*)(ws + OFF_CB);
    unsigned int* __restrict__ slb  = (unsigned int*)(ws + OFF_SLB);
    unsigned short* __restrict__ hbuf = (unsigned short*)(ws + OFF_HBUF);
    const float* __restrict__ bias = (const float*)(ws + OFF_BIAS);
    float* __restrict__ xih_base = (float*)(ws + OFF_XIH);

    if (blockIdx.x < 32) {
        // ================= LSTM recurrence =================
        const int bc = blockIdx.x;
        const int q = wv & 3;        // gate quadrant
        const int mh = wv >> 2;      // row half

        unsigned short* __restrict__ ghh = (unsigned short*)(ws + OFF_GHH);
        unsigned short* __restrict__ ghl = (unsigned short*)(ws + OFF_GHL);

        // ---- convert OWN W_hh slice (fp32 -> hi/lo bf16 fragments) ----
        bf16x8 bh[16], blo[16];
#pragma unroll
        for (int j = 0; j < 16; ++j) {
            const float* src = W_hh_f + (size_t)(q * 512 + bc * 16 + mf) * 512 + j * 32 + kg * 8;
            float4 w0 = *(const float4*)src;
            float4 w1 = *(const float4*)(src + 4);
            float ff[8] = {w0.x, w0.y, w0.z, w0.w, w1.x, w1.y, w1.z, w1.w};
#pragma unroll
            for (int e = 0; e < 8; ++e) {
                const unsigned short h = f2bf(ff[e]);
                bh[j][e] = (short)h;
                blo[j][e] = (short)f2bf(ff[e] - bf2f(h));
            }
        }

        // ---- per-thread cell mapping: 2 ADJACENT cols of one row ----
        const int crow = tid >> 3;           // batch row 0..63
        const int cp = tid & 7;              // col-pair 0..7
        const int c0 = bc * 16 + cp * 2;     // first hidden col
        const int jch = bc * 2 + (cp >> 2);  // chunk index (chunk-major layout)
        const int sw = (jch * 64 + crow) * 8 + ((cp * 2) & 7);  // elem offset
        float creg0 = 0.f, creg1 = 0.f;

        float2 xp[4];
        auto load_xp = [&](int tt) {
            const float* __restrict__ xq = xih_base + (size_t)tt * NB * G4;
#pragma unroll
            for (int g2 = 0; g2 < 4; ++g2)
                xp[g2] = *(const float2*)&xq[crow * G4 + g2 * 512 + c0];
        };

        // wait for xih slab 0 (workers produce it), then prefetch
        if (tid == 0) {
            while (__hip_atomic_load(&slb[0], __ATOMIC_RELAXED, __HIP_MEMORY_SCOPE_AGENT) < 16u)
                __builtin_amdgcn_s_sleep(1);
        }
        __syncthreads();
        load_xp(0);

        for (int t = 0; t < NT; ++t) {
            f32x4 accA[2], accB[2], accC[2];
#pragma unroll
            for (int m = 0; m < 2; ++m) {
                accA[m] = (f32x4){0.f, 0.f, 0.f, 0.f};
                accB[m] = (f32x4){0.f, 0.f, 0.f, 0.f};
                accC[m] = (f32x4){0.f, 0.f, 0.f, 0.f};
            }

            if (t > 0) {
                const int rd = (t + 1) & 1;
                const unsigned short* __restrict__ ghh_r = ghh + rd * (NB * NH);
                const unsigned short* __restrict__ ghl_r = ghl + rd * (NB * NH);

                // ---- combined spin: lanes 0-3 watch flagA of my 4 producers,
                //      lane 4 watches the xih slab counter; ballot exit ----
                {
                    const unsigned int* p = flgA + ((size_t)(t - 1) * 32 + bc) * FLGD;
                    unsigned int tgt = 0u;
                    if (lane < 4)       { p = flgA + ((size_t)(t - 1) * 32 + wv * 4 + lane) * FLGD; tgt = 1u; }
                    else if (lane == 4) { p = slb + (size_t)t * FLGD; tgt = 16u; }
                    while (__any(__hip_atomic_load(p, __ATOMIC_RELAXED, __HIP_MEMORY_SCOPE_AGENT) < tgt))
                        __builtin_amdgcn_s_sleep(1);
                }
                __builtin_amdgcn_sched_barrier(0);
                // ---- hi DMA: my 4 producers' slices (8 insts) ----
#pragma unroll
                for (int pp = 0; pp < 4; ++pp) {
                    const int jj = (wv * 4 + pp) * 2;   // chunk pair base
                    gl_lds16_sc(ghh_r + (jj    ) * 512 + lane * 8, &Hhi[(jj    ) * 512 + lane * 8]);
                    gl_lds16_sc(ghh_r + (jj + 1) * 512 + lane * 8, &Hhi[(jj + 1) * 512 + lane * 8]);
                }
                __builtin_amdgcn_sched_barrier(0);
                // ---- spinB: flagB of my producers (full drain: ghl+hbuf).
                //      The spin load's in-order retire also drains my hi DMAs. ----
                {
                    const unsigned int* p = flgB + ((size_t)(t - 1) * 32 + bc) * FLGD;
                    unsigned int tgt = 0u;
                    if (lane < 4) { p = flgB + ((size_t)(t - 1) * 32 + wv * 4 + lane) * FLGD; tgt = 1u; }
                    while (__any(__hip_atomic_load(p, __ATOMIC_RELAXED, __HIP_MEMORY_SCOPE_AGENT) < tgt))
                        __builtin_amdgcn_s_sleep(1);
                }
                __builtin_amdgcn_sched_barrier(0);
                // ---- lo DMA (8 insts) ----
#pragma unroll
                for (int pp = 0; pp < 4; ++pp) {
                    const int jj = (wv * 4 + pp) * 2;
                    gl_lds16_sc(ghl_r + (jj    ) * 512 + lane * 8, &Hlo[(jj    ) * 512 + lane * 8]);
                    gl_lds16_sc(ghl_r + (jj + 1) * 512 + lane * 8, &Hlo[(jj + 1) * 512 + lane * 8]);
                }
                // all waves' hi images complete (each drained its own via spinB)
                __builtin_amdgcn_s_barrier();
                load_xp(t);   // latency hides under hi MFMA
                // ---- hi passes: two INDEPENDENT accumulator chains ----
#pragma unroll
                for (int kt = 0; kt < 16; ++kt) {
                    const int j = kt * 4 + kg;
#pragma unroll
                    for (int m = 0; m < 2; ++m) {
                        const int row = mh * 32 + m * 16 + mf;
                        bf16x8 a_hi = *(const bf16x8*)&Hhi[(j * 64 + row) * 8];
                        accA[m] = __builtin_amdgcn_mfma_f32_16x16x32_bf16(a_hi, bh[kt], accA[m], 0, 0, 0);
                        accB[m] = __builtin_amdgcn_mfma_f32_16x16x32_bf16(a_hi, blo[kt], accB[m], 0, 0, 0);
                    }
                }
                asm volatile("s_waitcnt vmcnt(0)" ::: "memory");
                __builtin_amdgcn_s_barrier();
                // ---- lo pass: third independent chain ----
#pragma unroll
                for (int kt = 0; kt < 16; ++kt) {
                    const int j = kt * 4 + kg;
#pragma unroll
                    for (int m = 0; m < 2; ++m) {
                        const int row = mh * 32 + m * 16 + mf;
                        bf16x8 a_lo = *(const bf16x8*)&Hlo[(j * 64 + row) * 8];
                        accC[m] = __builtin_amdgcn_mfma_f32_16x16x32_bf16(a_lo, bh[kt], accC[m], 0, 0, 0);
                    }
                }
            }

            // ---- sum chains, gate values straight to LDS ----
#pragma unroll
            for (int m = 0; m < 2; ++m) {
                f32x4 acc = (accA[m] + accB[m]) + accC[m];
                const int row = mh * 32 + m * 16 + kg * 4;
#pragma unroll
                for (int r = 0; r < 4; ++r)
                    glf[(q * 64 + row + r) * 16 + mf] = acc[r];
            }
            __syncthreads();

            // ---- LSTM cell: 2 adjacent cols/thread, packed sc-stores ----
            {
                unsigned short* __restrict__ ghh_w = ghh + (t & 1) * (NB * NH);
                unsigned short* __restrict__ ghl_w = ghl + (t & 1) * (NB * NH);
                const float2 g0 = *(const float2*)&glf[(0 * 64 + crow) * 16 + cp * 2];
                const float2 g1 = *(const float2*)&glf[(1 * 64 + crow) * 16 + cp * 2];
                const float2 g2 = *(const float2*)&glf[(2 * 64 + crow) * 16 + cp * 2];
                const float2 g3 = *(const float2*)&glf[(3 * 64 + crow) * 16 + cp * 2];
                const float gi0 = g0.x + xp[0].x, gi1 = g0.y + xp[0].y;
                const float gf0 = g1.x + xp[1].x, gf1 = g1.y + xp[1].y;
                const float gg0 = g2.x + xp[2].x, gg1 = g2.y + xp[2].y;
                const float go0 = g3.x + xp[3].x, go1 = g3.y + xp[3].y;
                const float i0 = 1.f / (1.f + __expf(-gi0)), i1 = 1.f / (1.f + __expf(-gi1));
                const float f0 = 1.f / (1.f + __expf(-gf0)), f1 = 1.f / (1.f + __expf(-gf1));
                const float ga0 = tanhf_fast(gg0),           ga1 = tanhf_fast(gg1);
                const float o0 = 1.f / (1.f + __expf(-go0)), o1 = 1.f / (1.f + __expf(-go1));
                const float cn0 = f0 * creg0 + i0 * ga0;
                const float cn1 = f1 * creg1 + i1 * ga1;
                creg0 = cn0; creg1 = cn1;
                const float h0 = o0 * tanhf_fast(cn0);
                const float h1 = o1 * tanhf_fast(cn1);
                const unsigned short hi0 = f2bf(h0), hi1 = f2bf(h1);
                const unsigned short lo0 = f2bf(h0 - bf2f(hi0)), lo1 = f2bf(h1 - bf2f(hi1));
                const unsigned int hpack = (unsigned int)hi0 | ((unsigned int)hi1 << 16);
                const unsigned int lpack = (unsigned int)lo0 | ((unsigned int)lo1 << 16);
                // issue order matters: ghh FIRST (vmcnt(2) below proves it drained)
                st4_sc((unsigned int*)&ghh_w[sw], hpack);
                st4_sc((unsigned int*)&ghl_w[sw], lpack);
                const int sl = (t == 0) ? 0 : t - 1;   // t=0 dummy, overwritten at t=1
                st4_sc((unsigned int*)&hbuf[(size_t)sl * (NB * NH) + crow * NH + c0], hpack);
            }

            // ---- split-flag publish: flagA after ghh-only drain (vmcnt(2)),
            //      flagB after full drain. Raw barriers (no implicit vmcnt(0)). ----
            asm volatile("s_waitcnt vmcnt(2)" ::: "memory");   // oldest (ghh) retired
            __builtin_amdgcn_s_barrier();
            if (tid == 0) st4_sc(flgA + ((size_t)t * 32 + bc) * FLGD, 1u);
            asm volatile("s_waitcnt vmcnt(0)" ::: "memory");   // ghl + hbuf retired
            __builtin_amdgcn_s_barrier();
            if (tid == 0) st4_sc(flgB + ((size_t)t * 32 + bc) * FLGD, 1u);
        }
        asm volatile("s_waitcnt vmcnt(0)" ::: "memory");
        return;
    }

    // ================= workers =================
    const int g = blockIdx.x - 32;          // 0..223
    const int mw2 = (wv >> 2) * 32, nw2 = (wv & 3) * 32;

    // ---- stage 1: xih tiles (prep kernel already converted inputs) ----
    {
        const unsigned short* __restrict__ xh = (const unsigned short*)(ws + OFF_XSEQ_HI);
        const unsigned short* __restrict__ xl = (const unsigned short*)(ws + OFF_XSEQ_LO);
        const unsigned short* __restrict__ wih_h = (const unsigned short*)(ws + OFF_WIH_HI);
        const unsigned short* __restrict__ wih_l = (const unsigned short*)(ws + OFF_WIH_LO);

        unsigned short* Ah2 = Hhi;            // [2][2048] shorts
        unsigned short* Al2 = Hhi + 4096;
        unsigned short* Bh2 = Hhi + 8192;     // [2][4096] shorts
        unsigned short* Bl2 = Hhi + 16384;

        const int ntile = (g < 112) ? 2 : 1;
        for (int p = 0; p < ntile; ++p) {
            const int T = (p == 0) ? g : 224 + g;
            const int slab = T >> 4, ct = T & 15;
            const unsigned short* __restrict__ xhA = xh + (size_t)slab * 64 * 512;
            const unsigned short* __restrict__ xlA = xl + (size_t)slab * 64 * 512;

            auto stageA = [&](int buf, int k0) {
                if (tid < 256) {
                    const int s = tid, r = s >> 2, kc = (s & 3) * 8;
                    gl_lds16(xhA + (size_t)r * 512 + k0 + kc, &Ah2[buf * 2048 + s * 8]);
                    gl_lds16(xlA + (size_t)r * 512 + k0 + kc, &Al2[buf * 2048 + s * 8]);
                } else {
#pragma unroll
                    for (int h2 = 0; h2 < 2; ++h2) {
                        const int s = h2 * 256 + (tid - 256), r = s >> 2, kc = (s & 3) * 8;
                        gl_lds16(wih_h + (size_t)(ct * 128 + r) * 512 + k0 + kc, &Bh2[buf * 4096 + s * 8]);
                        gl_lds16(wih_l + (size_t)(ct * 128 + r) * 512 + k0 + kc, &Bl2[buf * 4096 + s * 8]);
                    }
                }
            };

            f32x4 acc2[2][2];
#pragma unroll
            for (int i = 0; i < 2; i++)
#pragma unroll
                for (int j = 0; j < 2; j++) acc2[i][j] = (f32x4){0.f, 0.f, 0.f, 0.f};

            stageA(0, 0);
            for (int kt = 0; kt < 16; ++kt) {
                __syncthreads();
                const int cur = kt & 1;
                if (kt < 15) stageA(cur ^ 1, (kt + 1) * 32);
                bf16x8 ah_[2], al_[2], bh_[2], bl_[2];
#pragma unroll
                for (int i = 0; i < 2; i++) {
                    ah_[i] = *(const bf16x8*)&Ah2[cur * 2048 + (mw2 + i * 16 + mf) * 32 + kg * 8];
                    al_[i] = *(const bf16x8*)&Al2[cur * 2048 + (mw2 + i * 16 + mf) * 32 + kg * 8];
                    bh_[i] = *(const bf16x8*)&Bh2[cur * 4096 + (nw2 + i * 16 + mf) * 32 + kg * 8];
                    bl_[i] = *(const bf16x8*)&Bl2[cur * 4096 + (nw2 + i * 16 + mf) * 32 + kg * 8];
                }
#pragma unroll
                for (int i = 0; i < 2; i++)
#pragma unroll
                    for (int j = 0; j < 2; j++) {
                        acc2[i][j] = __builtin_amdgcn_mfma_f32_16x16x32_bf16(ah_[i], bh_[j], acc2[i][j], 0, 0, 0);
                        acc2[i][j] = __builtin_amdgcn_mfma_f32_16x16x32_bf16(ah_[i], bl_[j], acc2[i][j], 0, 0, 0);
                        acc2[i][j] = __builtin_amdgcn_mfma_f32_16x16x32_bf16(al_[i], bh_[j], acc2[i][j], 0, 0, 0);
                    }
            }
            // epilogue: xih = acc + bias, sc-stores (visible mid-kernel)
#pragma unroll
            for (int i = 0; i < 2; i++)
#pragma unroll
                for (int j = 0; j < 2; j++) {
                    const int col = ct * 128 + nw2 + j * 16 + mf;
                    const float bb = bias[col];
#pragma unroll
                    for (int r = 0; r < 4; r++) {
                        const int row = slab * 64 + mw2 + i * 16 + kg * 4 + r;
                        st4_sc((unsigned int*)&xih_base[(size_t)row * G4 + col],
                               __float_as_uint(acc2[i][j][r] + bb));
                    }
                }
            asm volatile("s_waitcnt vmcnt(0)" ::: "memory");
            __syncthreads();   // all threads' xih stores at the coherence point
            if (tid == 0)
                __hip_atomic_fetch_add(&slb[slab * FLGD], 1u, __ATOMIC_RELAXED, __HIP_MEMORY_SCOPE_AGENT);
            __syncthreads();
        }
    }

    // ---- stage B: W_lin conversion (workers only; hidden under recurrence) ----
    {
        unsigned short* wlin_w = (unsigned short*)(ws + OFF_WLIN_HI);
        int idx = g * 512 + tid;
        for (int it = 0; it < 12; ++it, idx += 114688) {
            if (idx < 1280000) {
                const int i4 = idx * 4;
                float4 w = *(const float4*)(W_lin_f + i4);
                u16x4 hi;
                hi.x = f2bf(w.x); hi.y = f2bf(w.y); hi.z = f2bf(w.z); hi.w = f2bf(w.w);
                st8_sc(wlin_w + i4, hi);
            }
        }
        asm volatile("s_waitcnt vmcnt(0)" ::: "memory");
        __syncthreads();
        if (tid == 0) {
            __hip_atomic_fetch_add(&slb[25 * FLGD], 1u, __ATOMIC_RELAXED, __HIP_MEMORY_SCOPE_AGENT);
            while (__hip_atomic_load(&slb[25 * FLGD], __ATOMIC_RELAXED, __HIP_MEMORY_SCOPE_AGENT) < 224u)
                __builtin_amdgcn_s_sleep(1);
        }
        __syncthreads();
    }

    // ---- stage 2: streamed phase-C ----
    const unsigned short* __restrict__ wlin = (const unsigned short*)(ws + OFF_WLIN_HI);
    const int jt = g % 79;                  // fixed col tile -> B stays L2-resident
    const int rshare = g / 79;              // 0..2
    const int nshare = (jt < 66) ? 3 : 2;   // blocks sharing this col tile
    const int n0g = jt * 128;

    unsigned short* __restrict__ AsB = Hhi;          // [2][64*32]
    unsigned short* __restrict__ BsB = Hhi + 4096;   // [2][128*32]

    for (int tt = rshare; tt < NT - 1; tt += nshare) {
        // wait until h(tt+1) fully drained (flagB) == hbuf slab tt complete
        if (wv == 0) {
            const unsigned int* fp = flgB + ((size_t)(tt + 1) * 32 + (lane & 31)) * FLGD;
            while (__hip_atomic_load(fp, __ATOMIC_RELAXED, __HIP_MEMORY_SCOPE_AGENT) == 0u)
                __builtin_amdgcn_s_sleep(2);
        }
        __syncthreads();

        const unsigned short* __restrict__ hbA = hbuf + (size_t)tt * (NB * NH);
        auto stageC = [&](int buf, int k0) {
            if (tid < 256) {                 // waves 0..3: A (64x32), sc-reads
                const int s = tid;
                const int r = s >> 2, kcol = (s & 3) * 8;
                gl_lds16_sc(hbA + (size_t)r * 512 + k0 + kcol, &AsB[buf * 2048 + s * 8]);
            } else {                         // waves 4..7: B (128x32)
#pragma unroll
                for (int h2 = 0; h2 < 2; ++h2) {
                    const int s = h2 * 256 + (tid - 256);
                    const int r = s >> 2, kcol = (s & 3) * 8;
                    gl_lds16(wlin + (size_t)(n0g + r) * 512 + k0 + kcol, &BsB[buf * 4096 + s * 8]);
                }
            }
        };

        f32x4 acc2[2][2];
#pragma unroll
        for (int i = 0; i < 2; i++)
#pragma unroll
            for (int j = 0; j < 2; j++) acc2[i][j] = (f32x4){0.f, 0.f, 0.f, 0.f};

        stageC(0, 0);
        for (int kt = 0; kt < 16; ++kt) {
            __syncthreads();
            const int cur = kt & 1;
            if (kt < 15) stageC(cur ^ 1, (kt + 1) * 32);
            bf16x8 af[2], bfv[2];
#pragma unroll
            for (int i = 0; i < 2; i++) {
                af[i]  = *(const bf16x8*)&AsB[cur * 2048 + (mw2 + i * 16 + mf) * 32 + kg * 8];
                bfv[i] = *(const bf16x8*)&BsB[cur * 4096 + (nw2 + i * 16 + mf) * 32 + kg * 8];
            }
#pragma unroll
            for (int i = 0; i < 2; i++)
#pragma unroll
                for (int j = 0; j < 2; j++)
                    acc2[i][j] = __builtin_amdgcn_mfma_f32_16x16x32_bf16(af[i], bfv[j], acc2[i][j], 0, 0, 0);
        }
#pragma unroll
        for (int i = 0; i < 2; i++)
#pragma unroll
            for (int j = 0; j < 2; j++) {
                const int col = n0g + nw2 + j * 16 + mf;
                if (col < NV) {
                    const float bl = b_lin[col];
#pragma unroll
                    for (int r = 0; r < 4; r++) {
                        const int b_ = mw2 + i * 16 + kg * 4 + r;   // batch row
                        out[(size_t)b_ * ((NT - 1) * NV) + (size_t)tt * NV + col] = acc2[i][j][r] + bl;
                    }
                }
            }
        __syncthreads();   // tile reads done before next job restages
    }
}

extern "C" void kernel_launch(void* const* d_in, const int* in_sizes, int n_in,
                              void* d_out, int out_size, void* d_ws, size_t ws_size,
                              hipStream_t stream)
{
    const float* features = (const float*)d_in[0];
    const float* cap      = (const float*)d_in[1];
    const float* W_ih     = (const float*)d_in[2];
    const float* W_hh     = (const float*)d_in[3];
    const float* b_ih     = (const float*)d_in[4];
    const float* b_hh     = (const float*)d_in[5];
    const float* W_lin    = (const float*)d_in[6];
    const float* b_lin    = (const float*)d_in[7];
    float* out = (float*)d_out;
    unsigned char* ws = (unsigned char*)d_ws;

    // single contiguous memset: flagA + flagB + slab counters
    (void)hipMemsetAsync(ws + OFF_C, 0, 87680, stream);

    hipLaunchKernelGGL(prep_kernel, dim3(1698), dim3(256), 0, stream,
                       features, cap, W_ih, b_ih, b_hh, ws);
    hipLaunchKernelGGL(fused_all, dim3(256), dim3(512), 0, stream,
                       W_hh, W_lin, b_lin, out, ws);
}